// Round 4
// baseline (7082.614 us; speedup 1.0000x reference)
//
#include <hip/hip_runtime.h>
#include <math.h>

// ---------------------------------------------------------------------------
// Hierarchical bi-GRU (char bi-GRU -> word bi-GRU -> FC head), fp32.
//
// Decomposition:
//   gates = sigmoid(x@Wg_x + h@Wg_h + bg)      (x-part precomputed)
//   c     = tanh  (x@Wc_x + (r*h)@Wc_h + bc)
//   h'    = mask ? u*h + (1-u)*c : h
//
// char level : x-part is a 256-entry table (chars only take 256 values)
// word level : x-part = CTAB[charseq_id] (per unique word form) + wordemb-GEMM
// fw/bw share weights -> batched as one doubled batch (4096 / 512 rows)
// ---------------------------------------------------------------------------

#define TILE 64
#define BKK 16

enum AMode { A_PLAIN = 0, A_CHARSTATE = 1, A_RH = 2, A_GATHER = 3 };
enum EMode { E_BIAS = 0, E_GATE_CHAR = 1, E_CAND_CHAR = 2, E_XW = 3,
             E_GATE_WORD = 4, E_CAND_WORD = 5 };

struct GemmArgs {
  int M, N, K;
  const float* A; int lda;      // A_PLAIN/A_RH/A_GATHER: base matrix; A_CHARSTATE: Hc base [4096,512]
  const float* G; int ldg;      // A_RH: r-gates; E_CAND_*: u-gate source (cols 512..1023)
  const int*   arows;           // A_GATHER: per-row gather indices
  const float* B;               // [K,N] row-major, row stride == N
  const float* bias;            // E_BIAS
  const float* XT; int ldxt;    // epilogue additive table (x-part)
  const int*   seqs;            // charseqs (E_*_CHAR)
  const int*   lens;            // sequence lengths
  int t, T;
  const int*   cidx;            // E_XW: charseq_ids per row
  const float* Hin;             // E_CAND_*: previous h (row stride 512)
  float* Cout; int ldc;
};

__device__ __forceinline__ float sigmoidf_(float x) { return 1.0f / (1.0f + expf(-x)); }

template<int AM, int EM>
__global__ __launch_bounds__(256) void gemm_k(GemmArgs p) {
  __shared__ float As[BKK][TILE];
  __shared__ float Bs[BKK][TILE];
  const int tid = threadIdx.x;
  const int tx = tid & 15, ty = tid >> 4;
  const int m0 = blockIdx.y * TILE, n0 = blockIdx.x * TILE;
  const int la_r = tid >> 2, la_k = (tid & 3) << 2;   // A: 64 rows x 16 k, float4/thread
  const int lb_k = tid >> 4, lb_n = (tid & 15) << 2;  // B: 16 k x 64 n, float4/thread

  float acc[4][4] = {};

  int arow = 0;
  if constexpr (AM == A_GATHER) arow = p.arows[m0 + la_r];

  for (int k0 = 0; k0 < p.K; k0 += BKK) {
    float4 av;
    const int m = m0 + la_r;
    const int k = k0 + la_k;
    if constexpr (AM == A_PLAIN) {
      av = *reinterpret_cast<const float4*>(p.A + (size_t)m * p.lda + k);
    } else if constexpr (AM == A_CHARSTATE) {
      // concat(fw_state[m], bw_state[m]) over k in [0,1024)
      const float* ap = (k < 512) ? (p.A + (size_t)m * 512 + k)
                                  : (p.A + (size_t)(2048 + m) * 512 + (k - 512));
      av = *reinterpret_cast<const float4*>(ap);
    } else if constexpr (AM == A_RH) {
      float4 g = *reinterpret_cast<const float4*>(p.G + (size_t)m * p.ldg + k);
      float4 h = *reinterpret_cast<const float4*>(p.A + (size_t)m * p.lda + k);
      av = make_float4(g.x * h.x, g.y * h.y, g.z * h.z, g.w * h.w);
    } else { // A_GATHER
      av = *reinterpret_cast<const float4*>(p.A + (size_t)arow * p.lda + k);
    }
    As[la_k + 0][la_r] = av.x;
    As[la_k + 1][la_r] = av.y;
    As[la_k + 2][la_r] = av.z;
    As[la_k + 3][la_r] = av.w;
    float4 bv = *reinterpret_cast<const float4*>(p.B + (size_t)(k0 + lb_k) * p.N + n0 + lb_n);
    *reinterpret_cast<float4*>(&Bs[lb_k][lb_n]) = bv;
    __syncthreads();
#pragma unroll
    for (int kk = 0; kk < BKK; ++kk) {
      float4 a = *reinterpret_cast<const float4*>(&As[kk][ty << 2]);
      float4 b = *reinterpret_cast<const float4*>(&Bs[kk][tx << 2]);
      acc[0][0] += a.x * b.x; acc[0][1] += a.x * b.y; acc[0][2] += a.x * b.z; acc[0][3] += a.x * b.w;
      acc[1][0] += a.y * b.x; acc[1][1] += a.y * b.y; acc[1][2] += a.y * b.z; acc[1][3] += a.y * b.w;
      acc[2][0] += a.z * b.x; acc[2][1] += a.z * b.y; acc[2][2] += a.z * b.z; acc[2][3] += a.z * b.w;
      acc[3][0] += a.w * b.x; acc[3][1] += a.w * b.y; acc[3][2] += a.w * b.z; acc[3][3] += a.w * b.w;
    }
    __syncthreads();
  }

  const int rbase = m0 + (ty << 2);
  const int cbase = n0 + (tx << 2);
#pragma unroll
  for (int i = 0; i < 4; ++i) {
    const int row = rbase + i;
    if constexpr (EM == E_BIAS) {
#pragma unroll
      for (int j = 0; j < 4; ++j) {
        const int col = cbase + j;
        p.Cout[(size_t)row * p.ldc + col] = acc[i][j] + p.bias[col];
      }
    } else if constexpr (EM == E_GATE_CHAR || EM == E_CAND_CHAR) {
      const int us = row & 2047;
      const bool dir = row >= 2048;               // bw half of the batch
      const int len = p.lens[us];
      int pos = dir ? (len - 1 - p.t) : p.t;
      pos = pos < 0 ? 0 : (pos > p.T - 1 ? p.T - 1 : pos);
      const int ch = p.seqs[us * p.T + pos];
      const float* xrow = p.XT + (size_t)ch * p.ldxt;
      const bool mask = p.t < len;
#pragma unroll
      for (int j = 0; j < 4; ++j) {
        const int col = cbase + j;
        if constexpr (EM == E_GATE_CHAR) {
          p.Cout[(size_t)row * p.ldc + col] = sigmoidf_(acc[i][j] + xrow[col]);
        } else {
          const float cv = tanhf(acc[i][j] + xrow[col]);
          const float u  = p.G[(size_t)row * p.ldg + 512 + col];
          const float h  = p.Hin[(size_t)row * 512 + col];
          p.Cout[(size_t)row * p.ldc + col] = mask ? (u * h + (1.0f - u) * cv) : h;
        }
      }
    } else if constexpr (EM == E_XW) {
      const int cs = p.cidx[row];
      const float* xrow = p.XT + (size_t)cs * p.ldxt;
#pragma unroll
      for (int j = 0; j < 4; ++j) {
        const int col = cbase + j;
        p.Cout[(size_t)row * p.ldc + col] = acc[i][j] + xrow[col];
      }
    } else { // E_GATE_WORD / E_CAND_WORD
      const int b = row & 255;
      const bool dir = row >= 256;
      const int len = p.lens[b];
      int pos = dir ? (len - 1 - p.t) : p.t;
      pos = pos < 0 ? 0 : (pos > p.T - 1 ? p.T - 1 : pos);
      const float* xrow = p.XT + (size_t)(b * p.T + pos) * p.ldxt;
      const bool mask = p.t < len;
#pragma unroll
      for (int j = 0; j < 4; ++j) {
        const int col = cbase + j;
        if constexpr (EM == E_GATE_WORD) {
          p.Cout[(size_t)row * p.ldc + col] = sigmoidf_(acc[i][j] + xrow[col]);
        } else {
          const float cv = tanhf(acc[i][j] + xrow[col]);
          const float u  = p.G[(size_t)row * p.ldg + 512 + col];
          const float h  = p.Hin[(size_t)row * 512 + col];
          p.Cout[(size_t)row * p.ldc + col] = mask ? (u * h + (1.0f - u) * cv) : h;
        }
      }
    }
  }
}

// FC head: states = concat(fw,bw) [256,1024] -> leaky_relu(states@W1+b1,0.2) -> @W2+b2
__global__ __launch_bounds__(64) void head_k(const float* __restrict__ Hw,
                                             const float* __restrict__ W1,
                                             const float* __restrict__ b1,
                                             const float* __restrict__ W2,
                                             const float* __restrict__ b2,
                                             float* __restrict__ out) {
  __shared__ float s[1024];
  __shared__ float hid[64];
  const int b = blockIdx.x;
  const int tid = threadIdx.x;
  for (int k = tid; k < 512; k += 64) {
    s[k]       = Hw[(size_t)b * 512 + k];
    s[512 + k] = Hw[(size_t)(256 + b) * 512 + k];
  }
  __syncthreads();
  float acc = b1[tid];
  for (int k = 0; k < 1024; ++k) acc += s[k] * W1[k * 64 + tid];
  acc = acc > 0.0f ? acc : 0.2f * acc;  // leaky_relu alpha=0.2
  hid[tid] = acc;
  __syncthreads();
  if (tid < 2) {
    float a = b2[tid];
    for (int k = 0; k < 64; ++k) a += hid[k] * W2[k * 2 + tid];
    out[b * 2 + tid] = a;
  }
}

extern "C" void kernel_launch(void* const* d_in, const int* in_sizes, int n_in,
                              void* d_out, int out_size, void* d_ws, size_t ws_size,
                              hipStream_t stream) {
  const int*   charseqs      = (const int*)d_in[0];
  const int*   charseq_lens  = (const int*)d_in[1];
  const int*   charseq_ids   = (const int*)d_in[2];
  const int*   word_ids      = (const int*)d_in[3];
  const int*   sentence_lens = (const int*)d_in[4];
  const float* char_emb      = (const float*)d_in[5];
  const float* word_emb      = (const float*)d_in[6];
  const float* Wg_c          = (const float*)d_in[7];
  const float* bg_c          = (const float*)d_in[8];
  const float* Wc_c          = (const float*)d_in[9];
  const float* bc_c          = (const float*)d_in[10];
  const float* Wg_w          = (const float*)d_in[11];
  const float* bg_w          = (const float*)d_in[12];
  const float* Wc_w          = (const float*)d_in[13];
  const float* bc_w          = (const float*)d_in[14];
  const float* W1            = (const float*)d_in[15];
  const float* b1            = (const float*)d_in[16];
  const float* W2            = (const float*)d_in[17];
  const float* b2            = (const float*)d_in[18];
  float* out = (float*)d_out;

  float* ws = (float*)d_ws;
  size_t off = 0;
  auto alloc = [&](size_t n) { float* p = ws + off; off += n; return p; };
  float* XTABg = alloc(256 * 1024);           // char x-part gate table (+bg_c)
  float* XTABc = alloc(256 * 512);            // char x-part cand table (+bc_c)
  float* HcA   = alloc(4096 * 512);           // char GRU state ping
  float* HcB   = alloc(4096 * 512);           // char GRU state pong
  float* Gc    = alloc((size_t)4096 * 1024);  // char gates [r|u]
  float* CTABg = alloc((size_t)2048 * 1024);  // per-wordform gate x-part (+bg_w)
  float* CTABc = alloc((size_t)2048 * 512);
  float* XWg   = alloc((size_t)16384 * 1024); // per-(b,t) word gate x-part
  float* XWc   = alloc((size_t)16384 * 512);
  float* HwA   = alloc(512 * 512);
  float* HwB   = alloc(512 * 512);
  float* Gw    = alloc((size_t)512 * 1024);

  hipMemsetAsync(HcA, 0, (size_t)4096 * 512 * sizeof(float), stream);
  hipMemsetAsync(HwA, 0, (size_t)512 * 512 * sizeof(float), stream);

  // --- Stage A: char x-part tables  [256,128]@[128,1536] ---
  {
    GemmArgs a{}; a.M = 256; a.N = 1024; a.K = 128;
    a.A = char_emb; a.lda = 128; a.B = Wg_c; a.bias = bg_c; a.Cout = XTABg; a.ldc = 1024;
    gemm_k<A_PLAIN, E_BIAS><<<dim3(1024 / TILE, 256 / TILE), 256, 0, stream>>>(a);
    GemmArgs c{}; c.M = 256; c.N = 512; c.K = 128;
    c.A = char_emb; c.lda = 128; c.B = Wc_c; c.bias = bc_c; c.Cout = XTABc; c.ldc = 512;
    gemm_k<A_PLAIN, E_BIAS><<<dim3(512 / TILE, 256 / TILE), 256, 0, stream>>>(c);
  }

  // --- Stage B: char bi-GRU, 16 steps, batch 4096 (fw rows 0..2047, bw 2048..4095) ---
  float* hcur = HcA; float* hnext = HcB;
  for (int t = 0; t < 16; ++t) {
    GemmArgs g{}; g.M = 4096; g.N = 1024; g.K = 512;
    g.A = hcur; g.lda = 512; g.B = Wg_c + 128 * 1024;
    g.XT = XTABg; g.ldxt = 1024; g.seqs = charseqs; g.lens = charseq_lens; g.t = t; g.T = 16;
    g.Cout = Gc; g.ldc = 1024;
    gemm_k<A_PLAIN, E_GATE_CHAR><<<dim3(1024 / TILE, 4096 / TILE), 256, 0, stream>>>(g);

    GemmArgs c{}; c.M = 4096; c.N = 512; c.K = 512;
    c.A = hcur; c.lda = 512; c.G = Gc; c.ldg = 1024; c.B = Wc_c + 128 * 512;
    c.XT = XTABc; c.ldxt = 512; c.seqs = charseqs; c.lens = charseq_lens; c.t = t; c.T = 16;
    c.Hin = hcur; c.Cout = hnext; c.ldc = 512;
    gemm_k<A_RH, E_CAND_CHAR><<<dim3(512 / TILE, 4096 / TILE), 256, 0, stream>>>(c);

    float* tmp = hcur; hcur = hnext; hnext = tmp;
  }
  // after 16 steps hcur == HcA

  // --- Stage C: per-wordform x-part of word GRU  [2048,1024]@[1024,1536] ---
  {
    GemmArgs a{}; a.M = 2048; a.N = 1024; a.K = 1024;
    a.A = hcur; a.B = Wg_w; a.bias = bg_w; a.Cout = CTABg; a.ldc = 1024;
    gemm_k<A_CHARSTATE, E_BIAS><<<dim3(1024 / TILE, 2048 / TILE), 256, 0, stream>>>(a);
    GemmArgs c{}; c.M = 2048; c.N = 512; c.K = 1024;
    c.A = hcur; c.B = Wc_w; c.bias = bc_w; c.Cout = CTABc; c.ldc = 512;
    gemm_k<A_CHARSTATE, E_BIAS><<<dim3(512 / TILE, 2048 / TILE), 256, 0, stream>>>(c);
  }

  // --- Stage D: word-embedding x-part + CTAB gather  [16384,256]@[256,1536] ---
  {
    GemmArgs a{}; a.M = 16384; a.N = 1024; a.K = 256;
    a.A = word_emb; a.lda = 256; a.arows = word_ids; a.B = Wg_w + (size_t)1024 * 1024;
    a.XT = CTABg; a.ldxt = 1024; a.cidx = charseq_ids; a.Cout = XWg; a.ldc = 1024;
    gemm_k<A_GATHER, E_XW><<<dim3(1024 / TILE, 16384 / TILE), 256, 0, stream>>>(a);
    GemmArgs c{}; c.M = 16384; c.N = 512; c.K = 256;
    c.A = word_emb; c.lda = 256; c.arows = word_ids; c.B = Wc_w + (size_t)1024 * 512;
    c.XT = CTABc; c.ldxt = 512; c.cidx = charseq_ids; c.Cout = XWc; c.ldc = 512;
    gemm_k<A_GATHER, E_XW><<<dim3(512 / TILE, 16384 / TILE), 256, 0, stream>>>(c);
  }

  // --- Stage E: word bi-GRU, 64 steps, batch 512 (fw rows 0..255, bw 256..511) ---
  float* wcur = HwA; float* wnext = HwB;
  for (int t = 0; t < 64; ++t) {
    GemmArgs g{}; g.M = 512; g.N = 1024; g.K = 512;
    g.A = wcur; g.lda = 512; g.B = Wg_w + (size_t)1280 * 1024;
    g.XT = XWg; g.ldxt = 1024; g.lens = sentence_lens; g.t = t; g.T = 64;
    g.Cout = Gw; g.ldc = 1024;
    gemm_k<A_PLAIN, E_GATE_WORD><<<dim3(1024 / TILE, 512 / TILE), 256, 0, stream>>>(g);

    GemmArgs c{}; c.M = 512; c.N = 512; c.K = 512;
    c.A = wcur; c.lda = 512; c.G = Gw; c.ldg = 1024; c.B = Wc_w + (size_t)1280 * 512;
    c.XT = XWc; c.ldxt = 512; c.lens = sentence_lens; c.t = t; c.T = 64;
    c.Hin = wcur; c.Cout = wnext; c.ldc = 512;
    gemm_k<A_RH, E_CAND_WORD><<<dim3(512 / TILE, 512 / TILE), 256, 0, stream>>>(c);

    float* tmp = wcur; wcur = wnext; wnext = tmp;
  }
  // after 64 steps wcur == HwA

  // --- Stage F: FC head ---
  head_k<<<256, 64, 0, stream>>>(wcur, W1, b1, W2, b2, out);
}

// Round 5
// 5320.919 us; speedup vs baseline: 1.3311x; 1.3311x over previous
//
#include <hip/hip_runtime.h>
#include <math.h>

// ---------------------------------------------------------------------------
// Hierarchical bi-GRU (char bi-GRU -> word bi-GRU -> FC head), fp32.
//
//   gates = sigmoid(x@Wg_x + h@Wg_h + bg)      (x-part precomputed)
//   c     = tanh  (x@Wc_x + (r*h)@Wc_h + bc)
//   h'    = mask ? u*h + (1-u)*c : h
//
// The recurrences are ROW-INDEPENDENT, so each bi-GRU level is ONE persistent
// kernel: a block owns R rows, h lives in LDS, all T steps run inside with
// only __syncthreads(). Weights (3 MB) stream from L2 each step.
// char level : x-part is a 256-entry table; word level : XW = CTAB[cid] + we@W
// fw/bw share weights -> rows doubled (4096 / 512), dir uniform per block.
// ---------------------------------------------------------------------------

#define TILE 64
#define BKK 16

enum AMode { A_PLAIN = 0, A_CHARSTATE = 1, A_GATHER = 3 };
enum EMode { E_BIAS = 0, E_XW = 3 };

struct GemmArgs {
  int M, N, K;
  const float* A; int lda;      // A_PLAIN/A_GATHER base; A_CHARSTATE: Hc [4096,512]
  const int*   arows;           // A_GATHER row indices
  const float* B;               // [K,N] row-major
  const float* bias;            // E_BIAS
  const float* XT; int ldxt;    // E_XW additive table
  const int*   cidx;            // E_XW per-row table indices
  float* Cout; int ldc;
};

__device__ __forceinline__ float sigmoidf_(float x) { return 1.0f / (1.0f + expf(-x)); }

template<int AM, int EM>
__global__ __launch_bounds__(256) void gemm_k(GemmArgs p) {
  __shared__ float As[BKK][TILE];
  __shared__ float Bs[BKK][TILE];
  const int tid = threadIdx.x;
  const int tx = tid & 15, ty = tid >> 4;
  const int m0 = blockIdx.y * TILE, n0 = blockIdx.x * TILE;
  const int la_r = tid >> 2, la_k = (tid & 3) << 2;
  const int lb_k = tid >> 4, lb_n = (tid & 15) << 2;

  float acc[4][4] = {};
  int arow = 0;
  if constexpr (AM == A_GATHER) arow = p.arows[m0 + la_r];

  for (int k0 = 0; k0 < p.K; k0 += BKK) {
    float4 av;
    const int m = m0 + la_r;
    const int k = k0 + la_k;
    if constexpr (AM == A_PLAIN) {
      av = *reinterpret_cast<const float4*>(p.A + (size_t)m * p.lda + k);
    } else if constexpr (AM == A_CHARSTATE) {
      const float* ap = (k < 512) ? (p.A + (size_t)m * 512 + k)
                                  : (p.A + (size_t)(2048 + m) * 512 + (k - 512));
      av = *reinterpret_cast<const float4*>(ap);
    } else { // A_GATHER
      av = *reinterpret_cast<const float4*>(p.A + (size_t)arow * p.lda + k);
    }
    As[la_k + 0][la_r] = av.x;
    As[la_k + 1][la_r] = av.y;
    As[la_k + 2][la_r] = av.z;
    As[la_k + 3][la_r] = av.w;
    float4 bv = *reinterpret_cast<const float4*>(p.B + (size_t)(k0 + lb_k) * p.N + n0 + lb_n);
    *reinterpret_cast<float4*>(&Bs[lb_k][lb_n]) = bv;
    __syncthreads();
#pragma unroll
    for (int kk = 0; kk < BKK; ++kk) {
      float4 a = *reinterpret_cast<const float4*>(&As[kk][ty << 2]);
      float4 b = *reinterpret_cast<const float4*>(&Bs[kk][tx << 2]);
      acc[0][0] += a.x * b.x; acc[0][1] += a.x * b.y; acc[0][2] += a.x * b.z; acc[0][3] += a.x * b.w;
      acc[1][0] += a.y * b.x; acc[1][1] += a.y * b.y; acc[1][2] += a.y * b.z; acc[1][3] += a.y * b.w;
      acc[2][0] += a.z * b.x; acc[2][1] += a.z * b.y; acc[2][2] += a.z * b.z; acc[2][3] += a.z * b.w;
      acc[3][0] += a.w * b.x; acc[3][1] += a.w * b.y; acc[3][2] += a.w * b.z; acc[3][3] += a.w * b.w;
    }
    __syncthreads();
  }

  const int rbase = m0 + (ty << 2);
  const int cbase = n0 + (tx << 2);
#pragma unroll
  for (int i = 0; i < 4; ++i) {
    const int row = rbase + i;
    if constexpr (EM == E_BIAS) {
#pragma unroll
      for (int j = 0; j < 4; ++j) {
        const int col = cbase + j;
        p.Cout[(size_t)row * p.ldc + col] = acc[i][j] + p.bias[col];
      }
    } else { // E_XW
      const int cs = p.cidx[row];
      const float* xrow = p.XT + (size_t)cs * p.ldxt;
#pragma unroll
      for (int j = 0; j < 4; ++j) {
        const int col = cbase + j;
        p.Cout[(size_t)row * p.ldc + col] = acc[i][j] + xrow[col];
      }
    }
  }
}

// ---------------------------------------------------------------------------
// Persistent fused GRU: block owns R rows, T steps internal, h in LDS.
// Rows: [0,NU) = forward, [NU,2NU) = backward (dir uniform per block).
// Xg/Xc: CHARMODE ? 256-entry char tables : per-(b,t) XW tables (bias folded).
// ---------------------------------------------------------------------------
template<int R, int NU, int TT, bool CHARMODE>
__global__ __launch_bounds__(256) void gru_fused(
    const float* __restrict__ Whg,   // [512,1024] h-part of gate weights
    const float* __restrict__ Whc,   // [512,512]  h-part of cand weights
    const float* __restrict__ Xg,    // gate x-part table
    const float* __restrict__ Xc,    // cand x-part table
    const int*   __restrict__ lens,  // [NU]
    const int*   __restrict__ seqs,  // CHARMODE: [NU,TT]
    float* __restrict__ Hout)        // [2*NU, 512]
{
  __shared__ float h_s [R][512];
  __shared__ float rh_s[R][512];
  __shared__ float u_s [R][512];
  __shared__ int   seq_s[CHARMODE ? R * TT : 1];
  __shared__ int   xog_s[R];
  __shared__ int   xoc_s[R];
  __shared__ int   msk_s[R];

  const int tid  = threadIdx.x;
  const int row0 = blockIdx.x * R;
  const int us0  = row0 & (NU - 1);
  const bool bw  = row0 >= NU;

  for (int i = tid; i < R * 512; i += 256) h_s[i >> 9][i & 511] = 0.0f;
  if constexpr (CHARMODE) {
    for (int i = tid; i < R * TT; i += 256)
      seq_s[i] = seqs[(size_t)(us0 + i / TT) * TT + (i % TT)];
  }
  int mylen = 0;
  if (tid < R) mylen = lens[us0 + tid];
  __syncthreads();

  const int c0 = tid << 2;  // phase-1 cols (4 of 1024)
  const int c2 = tid << 1;  // phase-2 cols (2 of 512)

  for (int t = 0; t < TT; ++t) {
    // step context (one thread per row)
    if (tid < R) {
      int pos = bw ? (mylen - 1 - t) : t;
      pos = pos < 0 ? 0 : (pos > TT - 1 ? TT - 1 : pos);
      int xr;
      if constexpr (CHARMODE) xr = seq_s[tid * TT + pos];
      else                    xr = (us0 + tid) * TT + pos;
      xog_s[tid] = xr * 1024;
      xoc_s[tid] = xr * 512;
      msk_s[tid] = (t < mylen) ? 1 : 0;
    }
    __syncthreads();

    // ---- phase 1: gates = sigmoid(h @ Whg + Xg) ; produce rh / u in LDS ----
    float4 acc[R];
#pragma unroll
    for (int r = 0; r < R; ++r) acc[r] = make_float4(0.f, 0.f, 0.f, 0.f);
#pragma unroll 8
    for (int k = 0; k < 512; ++k) {
      const float4 w = *reinterpret_cast<const float4*>(Whg + (size_t)k * 1024 + c0);
#pragma unroll
      for (int r = 0; r < R; ++r) {
        const float hv = h_s[r][k];
        acc[r].x += hv * w.x; acc[r].y += hv * w.y;
        acc[r].z += hv * w.z; acc[r].w += hv * w.w;
      }
    }
#pragma unroll
    for (int r = 0; r < R; ++r) {
      const float4 x = *reinterpret_cast<const float4*>(Xg + xog_s[r] + c0);
      float4 g;
      g.x = sigmoidf_(acc[r].x + x.x);
      g.y = sigmoidf_(acc[r].y + x.y);
      g.z = sigmoidf_(acc[r].z + x.z);
      g.w = sigmoidf_(acc[r].w + x.w);
      if (c0 < 512) {        // r-gate cols -> rh = r * h
        const float4 hh = *reinterpret_cast<const float4*>(&h_s[r][c0]);
        rh_s[r][c0 + 0] = g.x * hh.x;
        rh_s[r][c0 + 1] = g.y * hh.y;
        rh_s[r][c0 + 2] = g.z * hh.z;
        rh_s[r][c0 + 3] = g.w * hh.w;
      } else {               // u-gate cols
        u_s[r][c0 - 512 + 0] = g.x;
        u_s[r][c0 - 512 + 1] = g.y;
        u_s[r][c0 - 512 + 2] = g.z;
        u_s[r][c0 - 512 + 3] = g.w;
      }
    }
    __syncthreads();

    // ---- phase 2: c = tanh(rh @ Whc + Xc) ; h' = mask? u*h+(1-u)*c : h ----
    float2 acc2[R];
#pragma unroll
    for (int r = 0; r < R; ++r) acc2[r] = make_float2(0.f, 0.f);
#pragma unroll 8
    for (int k = 0; k < 512; ++k) {
      const float2 w = *reinterpret_cast<const float2*>(Whc + (size_t)k * 512 + c2);
#pragma unroll
      for (int r = 0; r < R; ++r) {
        const float rv = rh_s[r][k];
        acc2[r].x += rv * w.x; acc2[r].y += rv * w.y;
      }
    }
#pragma unroll
    for (int r = 0; r < R; ++r) {
      const float2 x = *reinterpret_cast<const float2*>(Xc + xoc_s[r] + c2);
      const float cx = tanhf(acc2[r].x + x.x);
      const float cy = tanhf(acc2[r].y + x.y);
      if (msk_s[r]) {
        const float ux = u_s[r][c2], uy = u_s[r][c2 + 1];
        const float hx = h_s[r][c2], hy = h_s[r][c2 + 1];
        h_s[r][c2]     = ux * hx + (1.0f - ux) * cx;
        h_s[r][c2 + 1] = uy * hy + (1.0f - uy) * cy;
      }
    }
    __syncthreads();
  }

  for (int i = tid; i < R * 512; i += 256)
    Hout[(size_t)(row0 + (i >> 9)) * 512 + (i & 511)] = h_s[i >> 9][i & 511];
}

// FC head: states = concat(fw,bw) [256,1024] -> leaky_relu(@W1+b1,0.2) -> @W2+b2
__global__ __launch_bounds__(64) void head_k(const float* __restrict__ Hw,
                                             const float* __restrict__ W1,
                                             const float* __restrict__ b1,
                                             const float* __restrict__ W2,
                                             const float* __restrict__ b2,
                                             float* __restrict__ out) {
  __shared__ float s[1024];
  __shared__ float hid[64];
  const int b = blockIdx.x;
  const int tid = threadIdx.x;
  for (int k = tid; k < 512; k += 64) {
    s[k]       = Hw[(size_t)b * 512 + k];
    s[512 + k] = Hw[(size_t)(256 + b) * 512 + k];
  }
  __syncthreads();
  float acc = b1[tid];
  for (int k = 0; k < 1024; ++k) acc += s[k] * W1[k * 64 + tid];
  acc = acc > 0.0f ? acc : 0.2f * acc;
  hid[tid] = acc;
  __syncthreads();
  if (tid < 2) {
    float a = b2[tid];
    for (int k = 0; k < 64; ++k) a += hid[k] * W2[k * 2 + tid];
    out[b * 2 + tid] = a;
  }
}

extern "C" void kernel_launch(void* const* d_in, const int* in_sizes, int n_in,
                              void* d_out, int out_size, void* d_ws, size_t ws_size,
                              hipStream_t stream) {
  const int*   charseqs      = (const int*)d_in[0];
  const int*   charseq_lens  = (const int*)d_in[1];
  const int*   charseq_ids   = (const int*)d_in[2];
  const int*   word_ids      = (const int*)d_in[3];
  const int*   sentence_lens = (const int*)d_in[4];
  const float* char_emb      = (const float*)d_in[5];
  const float* word_emb      = (const float*)d_in[6];
  const float* Wg_c          = (const float*)d_in[7];
  const float* bg_c          = (const float*)d_in[8];
  const float* Wc_c          = (const float*)d_in[9];
  const float* bc_c          = (const float*)d_in[10];
  const float* Wg_w          = (const float*)d_in[11];
  const float* bg_w          = (const float*)d_in[12];
  const float* Wc_w          = (const float*)d_in[13];
  const float* bc_w          = (const float*)d_in[14];
  const float* W1            = (const float*)d_in[15];
  const float* b1            = (const float*)d_in[16];
  const float* W2            = (const float*)d_in[17];
  const float* b2            = (const float*)d_in[18];
  float* out = (float*)d_out;

  float* ws = (float*)d_ws;
  size_t off = 0;
  auto alloc = [&](size_t n) { float* p = ws + off; off += n; return p; };
  float* XTABg = alloc(256 * 1024);            // char gate x-part (+bg_c)
  float* XTABc = alloc(256 * 512);             // char cand x-part (+bc_c)
  float* Hc    = alloc((size_t)4096 * 512);    // char bi-GRU final states
  float* CTABg = alloc((size_t)2048 * 1024);   // per-wordform gate x-part (+bg_w)
  float* CTABc = alloc((size_t)2048 * 512);
  float* XWg   = alloc((size_t)16384 * 1024);  // per-(b,t) word gate x-part
  float* XWc   = alloc((size_t)16384 * 512);
  float* Hw    = alloc(512 * 512);             // word bi-GRU final states

  // --- Stage A: char x-part tables  [256,128]@[128,1536] ---
  {
    GemmArgs a{}; a.M = 256; a.N = 1024; a.K = 128;
    a.A = char_emb; a.lda = 128; a.B = Wg_c; a.bias = bg_c; a.Cout = XTABg; a.ldc = 1024;
    gemm_k<A_PLAIN, E_BIAS><<<dim3(1024 / TILE, 256 / TILE), 256, 0, stream>>>(a);
    GemmArgs c{}; c.M = 256; c.N = 512; c.K = 128;
    c.A = char_emb; c.lda = 128; c.B = Wc_c; c.bias = bc_c; c.Cout = XTABc; c.ldc = 512;
    gemm_k<A_PLAIN, E_BIAS><<<dim3(512 / TILE, 256 / TILE), 256, 0, stream>>>(c);
  }

  // --- Stage B: fused char bi-GRU (4096 rows, 16 steps, R=8 -> 512 blocks) ---
  gru_fused<8, 2048, 16, true><<<512, 256, 0, stream>>>(
      Wg_c + 128 * 1024, Wc_c + 128 * 512, XTABg, XTABc,
      charseq_lens, charseqs, Hc);

  // --- Stage C: per-wordform x-part of word GRU  [2048,1024]@[1024,1536] ---
  {
    GemmArgs a{}; a.M = 2048; a.N = 1024; a.K = 1024;
    a.A = Hc; a.B = Wg_w; a.bias = bg_w; a.Cout = CTABg; a.ldc = 1024;
    gemm_k<A_CHARSTATE, E_BIAS><<<dim3(1024 / TILE, 2048 / TILE), 256, 0, stream>>>(a);
    GemmArgs c{}; c.M = 2048; c.N = 512; c.K = 1024;
    c.A = Hc; c.B = Wc_w; c.bias = bc_w; c.Cout = CTABc; c.ldc = 512;
    gemm_k<A_CHARSTATE, E_BIAS><<<dim3(512 / TILE, 2048 / TILE), 256, 0, stream>>>(c);
  }

  // --- Stage D: word-emb x-part + CTAB gather  [16384,256]@[256,1536] ---
  {
    GemmArgs a{}; a.M = 16384; a.N = 1024; a.K = 256;
    a.A = word_emb; a.lda = 256; a.arows = word_ids; a.B = Wg_w + (size_t)1024 * 1024;
    a.XT = CTABg; a.ldxt = 1024; a.cidx = charseq_ids; a.Cout = XWg; a.ldc = 1024;
    gemm_k<A_GATHER, E_XW><<<dim3(1024 / TILE, 16384 / TILE), 256, 0, stream>>>(a);
    GemmArgs c{}; c.M = 16384; c.N = 512; c.K = 256;
    c.A = word_emb; c.lda = 256; c.arows = word_ids; c.B = Wc_w + (size_t)1024 * 512;
    c.XT = CTABc; c.ldxt = 512; c.cidx = charseq_ids; c.Cout = XWc; c.ldc = 512;
    gemm_k<A_GATHER, E_XW><<<dim3(512 / TILE, 16384 / TILE), 256, 0, stream>>>(c);
  }

  // --- Stage E: fused word bi-GRU (512 rows, 64 steps, R=2 -> 256 blocks) ---
  gru_fused<2, 256, 64, false><<<256, 256, 0, stream>>>(
      Wg_w + (size_t)1280 * 1024, Wc_w + (size_t)1280 * 512, XWg, XWc,
      sentence_lens, nullptr, Hw);

  // --- Stage F: FC head ---
  head_k<<<256, 64, 0, stream>>>(Hw, W1, b1, W2, b2, out);
}